// Round 3
// baseline (201.311 us; speedup 1.0000x reference)
//
#include <hip/hip_runtime.h>
#include <math.h>

#define BATCH    4096
#define ND       13
#define NS       26
#define VOCAB    10000
#define NFIELD   39
#define KDIM     8
#define ROW      312              // floats per v row (39*8)
#define NSLOT    78               // float4 slots per v row (312/4)
#define RPB      2                // batch rows per block
#define NT       256              // 4 waves; 2 waves per batch row
#define NREP     8                // diagnostic: 8 serial launches to separate
                                  // fixed replay overhead F from kernel time t

typedef float f4 __attribute__((ext_vector_type(4)));

__global__ __launch_bounds__(NT) void ffm_kernel(
    const float* __restrict__ dense_x,   // (B, 13)
    const int*   __restrict__ sparse_x,  // (B, 26)
    const float* __restrict__ w0,        // (1,)
    const float* __restrict__ w,         // (260013, 1)
    const float* __restrict__ v,         // (260013, 39, 8)
    float*       __restrict__ out)       // (B, 1)
{
    const int t    = threadIdx.x;
    const int h    = t >> 7;             // which batch row within block (0/1)
    const int lt   = t & 127;            // slot within half-block
    const int b    = blockIdx.x * RPB + h;
    const int wv   = t >> 6;             // wave id 0..3
    const int lane = t & 63;

    __shared__ int   s_idx[RPB][NS];
    __shared__ float s_dense[RPB][ND];
    __shared__ f4    s_sA[4];            // per-wave partial s[0..3] (even-parity lanes)
    __shared__ f4    s_sB[4];            // per-wave partial s[4..7] (odd-parity lanes)
    __shared__ float s_sq[4];            // per-wave sum of squares
    __shared__ float s_lin[RPB];

    if (lt < NS)
        s_idx[h][lt] = ND + lt * VOCAB + sparse_x[b * NS + lt];
    if (lt >= 32 && lt < 32 + ND)
        s_dense[h][lt - 32] = dense_x[b * ND + (lt - 32)];
    __syncthreads();

    // ---- linear term: first wave of each half, lanes 0..39 in parallel ----
    if ((lt >> 6) == 0) {
        float li = 0.f;
        if (lane < NS)                li = w[s_idx[h][lane]];
        else if (lane < NS + ND)      li = s_dense[h][lane - NS] * w[lane - NS];
        else if (lane == NS + ND)     li = w0[0];
#pragma unroll
        for (int m = 32; m >= 1; m >>= 1) li += __shfl_xor(li, m, 64);
        if (lane == 0) s_lin[h] = li;
    }

    // ---- field_f accumulation: thread owns float4 slot lt (floats 4lt..4lt+3) ----
    f4 acc = 0.f;
    if (lt < NSLOT) {
        const f4* vp = (const f4*)v;
        // dense part: v[:13] (16 KB) stays L2-resident
#pragma unroll
        for (int d = 0; d < ND; ++d)
            acc += s_dense[h][d] * vp[d * NSLOT + lt];
        // sparse gathers: uniform row base in SGPR, 16B/lane coalesced
#pragma unroll
        for (int j = 0; j < NS; ++j) {
            int idx = __builtin_amdgcn_readfirstlane(s_idx[h][j]);
            const f4* rowp = (const f4*)(v + (size_t)idx * ROW);
            acc += rowp[lt];
        }
    }

    // ---- reductions ----
    // sum of squares across all slots of this half (via per-wave + LDS)
    float sq = acc[0]*acc[0] + acc[1]*acc[1] + acc[2]*acc[2] + acc[3]*acc[3];
#pragma unroll
    for (int m = 32; m >= 1; m >>= 1) sq += __shfl_xor(sq, m, 64);

    // per-k sums: even slots hold k=0..3, odd slots hold k=4..7; slot parity == lane parity
    f4 sv = acc;
#pragma unroll
    for (int m = 32; m >= 2; m >>= 1) {
        sv[0] += __shfl_xor(sv[0], m, 64);
        sv[1] += __shfl_xor(sv[1], m, 64);
        sv[2] += __shfl_xor(sv[2], m, 64);
        sv[3] += __shfl_xor(sv[3], m, 64);
    }
    if (lane == 0) { s_sA[wv] = sv; s_sq[wv] = sq; }
    if (lane == 1) { s_sB[wv] = sv; }
    __syncthreads();

    // ---- epilogue: one thread per batch row ----
    if (lt == 0) {
        f4 A = s_sA[2*h] + s_sA[2*h + 1];     // s[0..3]
        f4 B = s_sB[2*h] + s_sB[2*h + 1];     // s[4..7]
        float ssum  = A[0]*A[0] + A[1]*A[1] + A[2]*A[2] + A[3]*A[3]
                    + B[0]*B[0] + B[1]*B[1] + B[2]*B[2] + B[3]*B[3];
        float sumsq = s_sq[2*h] + s_sq[2*h + 1];
        float total = s_lin[h] + 0.5f * (ssum - sumsq);
        out[b] = 1.f / (1.f + expf(-total));
    }
}

extern "C" void kernel_launch(void* const* d_in, const int* in_sizes, int n_in,
                              void* d_out, int out_size, void* d_ws, size_t ws_size,
                              hipStream_t stream) {
    const float* dense_x  = (const float*)d_in[0];
    const int*   sparse_x = (const int*)d_in[1];
    const float* w0       = (const float*)d_in[2];
    const float* w        = (const float*)d_in[3];
    const float* v        = (const float*)d_in[4];
    float* out = (float*)d_out;

    // DIAGNOSTIC ROUND: 8 identical serial launches (idempotent — each writes
    // the same out[]). dur8 = F + 8t + 7g; with round-2's dur1 = F + t = 29.25,
    // (dur8 - 29.25)/7 isolates per-kernel time t+g. Decides H1 (kernel ~29us,
    // headroom real) vs H2 (kernel ~20us at gather roofline + ~9us fixed
    // replay overhead). Next round reverts to a single launch.
    for (int rep = 0; rep < NREP; ++rep) {
        hipLaunchKernelGGL(ffm_kernel, dim3(BATCH / RPB), dim3(NT), 0, stream,
                           dense_x, sparse_x, w0, w, v, out);
    }
}

// Round 4
// 28.990 us; speedup vs baseline: 6.9442x; 6.9442x over previous
//
#include <hip/hip_runtime.h>
#include <math.h>

#define BATCH    4096
#define ND       13
#define NS       26
#define VOCAB    10000
#define NFIELD   39
#define KDIM     8
#define ROW      312              // floats per v row (39*8)
#define NSLOT    78               // float4 slots per v row (312/4)
#define RPB      2                // batch rows per block
#define NT       256              // 4 waves; 2 waves per batch row

// Roofline note (R3 diagnostic): 8x serial launches gave marginal kernel time
// ~24 us = 148 MB line-granular gather traffic at ~6.1 TB/s ~= m13's measured
// 10 B/cyc/CU HBM ceiling. Single-launch dur_us carries ~5 us fixed replay
// overhead. Traffic is irreducible (all 312 floats of each gathered row are
// consumed; w table is L2-resident; no persistent scratch allowed).

typedef float f4 __attribute__((ext_vector_type(4)));

__global__ __launch_bounds__(NT) void ffm_kernel(
    const float* __restrict__ dense_x,   // (B, 13)
    const int*   __restrict__ sparse_x,  // (B, 26)
    const float* __restrict__ w0,        // (1,)
    const float* __restrict__ w,         // (260013, 1)
    const float* __restrict__ v,         // (260013, 39, 8)
    float*       __restrict__ out)       // (B, 1)
{
    const int t    = threadIdx.x;
    const int h    = t >> 7;             // which batch row within block (0/1)
    const int lt   = t & 127;            // slot within half-block
    const int b    = blockIdx.x * RPB + h;
    const int wv   = t >> 6;             // wave id 0..3
    const int lane = t & 63;

    __shared__ int   s_idx[RPB][NS];
    __shared__ float s_dense[RPB][ND];
    __shared__ f4    s_sA[4];            // per-wave partial s[0..3] (even-parity lanes)
    __shared__ f4    s_sB[4];            // per-wave partial s[4..7] (odd-parity lanes)
    __shared__ float s_sq[4];            // per-wave sum of squares
    __shared__ float s_lin[RPB];

    if (lt < NS)
        s_idx[h][lt] = ND + lt * VOCAB + sparse_x[b * NS + lt];
    if (lt >= 32 && lt < 32 + ND)
        s_dense[h][lt - 32] = dense_x[b * ND + (lt - 32)];
    __syncthreads();

    // ---- linear term: first wave of each half, lanes 0..39 in parallel ----
    if ((lt >> 6) == 0) {
        float li = 0.f;
        if (lane < NS)                li = w[s_idx[h][lane]];
        else if (lane < NS + ND)      li = s_dense[h][lane - NS] * w[lane - NS];
        else if (lane == NS + ND)     li = w0[0];
#pragma unroll
        for (int m = 32; m >= 1; m >>= 1) li += __shfl_xor(li, m, 64);
        if (lane == 0) s_lin[h] = li;
    }

    // ---- field_f accumulation: thread owns float4 slot lt (floats 4lt..4lt+3) ----
    f4 acc = 0.f;
    if (lt < NSLOT) {
        const f4* vp = (const f4*)v;
        // dense part: v[:13] (16 KB) stays L2-resident
#pragma unroll
        for (int d = 0; d < ND; ++d)
            acc += s_dense[h][d] * vp[d * NSLOT + lt];
        // sparse gathers: uniform row base in SGPR, 16B/lane coalesced
#pragma unroll
        for (int j = 0; j < NS; ++j) {
            int idx = __builtin_amdgcn_readfirstlane(s_idx[h][j]);
            const f4* rowp = (const f4*)(v + (size_t)idx * ROW);
            acc += rowp[lt];
        }
    }

    // ---- reductions ----
    // sum of squares across all slots of this half (via per-wave + LDS)
    float sq = acc[0]*acc[0] + acc[1]*acc[1] + acc[2]*acc[2] + acc[3]*acc[3];
#pragma unroll
    for (int m = 32; m >= 1; m >>= 1) sq += __shfl_xor(sq, m, 64);

    // per-k sums: even slots hold k=0..3, odd slots hold k=4..7; slot parity == lane parity
    f4 sv = acc;
#pragma unroll
    for (int m = 32; m >= 2; m >>= 1) {
        sv[0] += __shfl_xor(sv[0], m, 64);
        sv[1] += __shfl_xor(sv[1], m, 64);
        sv[2] += __shfl_xor(sv[2], m, 64);
        sv[3] += __shfl_xor(sv[3], m, 64);
    }
    if (lane == 0) { s_sA[wv] = sv; s_sq[wv] = sq; }
    if (lane == 1) { s_sB[wv] = sv; }
    __syncthreads();

    // ---- epilogue: one thread per batch row ----
    if (lt == 0) {
        f4 A = s_sA[2*h] + s_sA[2*h + 1];     // s[0..3]
        f4 B = s_sB[2*h] + s_sB[2*h + 1];     // s[4..7]
        float ssum  = A[0]*A[0] + A[1]*A[1] + A[2]*A[2] + A[3]*A[3]
                    + B[0]*B[0] + B[1]*B[1] + B[2]*B[2] + B[3]*B[3];
        float sumsq = s_sq[2*h] + s_sq[2*h + 1];
        float total = s_lin[h] + 0.5f * (ssum - sumsq);
        out[b] = 1.f / (1.f + expf(-total));
    }
}

extern "C" void kernel_launch(void* const* d_in, const int* in_sizes, int n_in,
                              void* d_out, int out_size, void* d_ws, size_t ws_size,
                              hipStream_t stream) {
    const float* dense_x  = (const float*)d_in[0];
    const int*   sparse_x = (const int*)d_in[1];
    const float* w0       = (const float*)d_in[2];
    const float* w        = (const float*)d_in[3];
    const float* v        = (const float*)d_in[4];
    float* out = (float*)d_out;

    hipLaunchKernelGGL(ffm_kernel, dim3(BATCH / RPB), dim3(NT), 0, stream,
                       dense_x, sparse_x, w0, w, v, out);
}